// Round 1
// baseline (445.736 us; speedup 1.0000x reference)
//
#include <hip/hip_runtime.h>
#include <hip/hip_bf16.h>
#include <cstdint>
#include <cstddef>

#define NN     8192
#define INF_   256
#define OUTF   128
#define ALPHA  0.2f
#define LOG2E  1.4426950408889634f
#define JSPLIT 8
#define CHUNK  (NN / JSPLIT)   // 1024 j per block

typedef __bf16 bf16;
typedef unsigned int u32;
typedef unsigned long long u64;
typedef __attribute__((ext_vector_type(8))) __bf16 bf16x8;
typedef __attribute__((ext_vector_type(4))) float f32x4;
typedef __attribute__((ext_vector_type(4))) int i32x4;
typedef __attribute__((ext_vector_type(4))) unsigned int u32x4;
typedef __attribute__((ext_vector_type(8))) unsigned short u16x8;
typedef __attribute__((ext_vector_type(4))) unsigned short u16x4;

// ---------------------------------------------------------------------------
// Dtype detector: read x's first 2048 uint16s as bf16. fp32 storage -> words
// are fp32 mantissa fragments -> huge exponents; bf16 storage -> N(0,1).
// flag = 1 -> tensors are fp32 (confirmed R2-R7); 0 -> bf16.
// ---------------------------------------------------------------------------
__global__ void gat_detect(const unsigned short* __restrict__ xr, int* __restrict__ flag)
{
    const int lane = threadIdx.x & 63;
    float m = 0.f;
    #pragma unroll
    for (int t = 0; t < 32; ++t) {
        const unsigned short u = xr[lane * 32 + t];
        const float v = fabsf((float)__builtin_bit_cast(bf16, u));
        if (v == v) m = fmaxf(m, v);
    }
    #pragma unroll
    for (int d = 1; d < 64; d <<= 1) m = fmaxf(m, __shfl_xor(m, d));
    if (lane == 0) *flag = (m > 100.f) ? 1 : 0;
}

// dtype-generic helpers ------------------------------------------------------
static __device__ __forceinline__ bf16  loadS(const bf16* p)  { return *p; }
static __device__ __forceinline__ bf16  loadS(const float* p) { return (bf16)*p; }
static __device__ __forceinline__ float loadF(const bf16* p)  { return (float)*p; }
static __device__ __forceinline__ float loadF(const float* p) { return *p; }
static __device__ __forceinline__ void load4(const float* p, bf16* d) {
    const f32x4 v = *(const f32x4*)p;
    #pragma unroll
    for (int t = 0; t < 4; ++t) d[t] = (bf16)v[t];
}
static __device__ __forceinline__ void load4(const bf16* p, bf16* d) {
    *(u16x4*)d = *(const u16x4*)p;
}

// ---------------------------------------------------------------------------
// trans transpose: TT[n][k] = bf16(trans[k][n]).
// ---------------------------------------------------------------------------
template <typename T, int WANT>
__global__ void gat_tt(const T* __restrict__ trans, const int* __restrict__ flag,
                       bf16* __restrict__ TT)
{
    if (*flag != WANT) return;
    const int n = blockIdx.x;      // 0..127
    const int k = threadIdx.x;     // 0..255
    TT[n * INF_ + k] = loadS(trans + k * OUTF + n);
}

// ---------------------------------------------------------------------------
// Projection: h = x @ trans via LDS-staged MFMA. Outputs:
//   HTt tiled: HTt[i>>5][n][i&31]  (attn b-frag loads become contiguous 1KB)
//   e1c/e2c (pre-scaled by log2e)
// ---------------------------------------------------------------------------
template <typename T, int WANT>
__global__ __launch_bounds__(256, 1)
void gat_proj_t(const T* __restrict__ x, const bf16* __restrict__ TT,
                const T* __restrict__ aw, const int* __restrict__ flag,
                bf16* __restrict__ HTt, float* __restrict__ e1c, float* __restrict__ e2c)
{
    if (*flag != WANT) return;

    __shared__ bf16  xs[32][264];
    __shared__ bf16  TTs[128][264];
    __shared__ float hl[32][129];

    const int tid  = threadIdx.x;
    const int wave = tid >> 6;
    const int lane = tid & 63;
    const int m    = lane & 15;
    const int q    = lane >> 4;
    const int i0   = blockIdx.x * 32;

    #pragma unroll
    for (int it = 0; it < 8; ++it) {
        const int e = it * 1024 + tid * 4;
        bf16 tmp[4];
        load4(x + (size_t)i0 * INF_ + e, tmp);
        *(u16x4*)&xs[e >> 8][e & 255] = *(u16x4*)tmp;
    }
    #pragma unroll
    for (int it = 0; it < 16; ++it) {
        const int e = it * 2048 + tid * 8;
        *(u16x8*)&TTs[e >> 8][e & 255] = *(const u16x8*)(TT + e);
    }
    __syncthreads();

    const int rh = wave & 1, fh = wave >> 1;
    f32x4 acc[4] = {};
    #pragma unroll
    for (int ks = 0; ks < INF_; ks += 32) {
        const bf16x8 a = *(const bf16x8*)&xs[rh * 16 + m][ks + q * 8];
        #pragma unroll
        for (int tn = 0; tn < 4; ++tn) {
            const bf16x8 b = *(const bf16x8*)&TTs[fh * 64 + tn * 16 + m][ks + q * 8];
            acc[tn] = __builtin_amdgcn_mfma_f32_16x16x32_bf16(a, b, acc[tn], 0, 0, 0);
        }
    }

    #pragma unroll
    for (int tn = 0; tn < 4; ++tn)
        #pragma unroll
        for (int r = 0; r < 4; ++r)
            hl[rh * 16 + q * 4 + r][fh * 64 + tn * 16 + m] = acc[tn][r];
    __syncthreads();

    {   // e1/e2
        const int r = tid >> 3, seg = tid & 7;
        float s1 = 0.f, s2 = 0.f;
        #pragma unroll
        for (int u = 0; u < 16; ++u) {
            const float hv = hl[r][seg * 16 + u];
            s1 += hv * loadF(aw + seg * 16 + u);
            s2 += hv * loadF(aw + OUTF + seg * 16 + u);
        }
        #pragma unroll
        for (int d = 1; d < 8; d <<= 1) {
            s1 += __shfl_xor(s1, d);
            s2 += __shfl_xor(s2, d);
        }
        if (seg == 0) {
            e1c[i0 + r] = s1 * LOG2E;
            e2c[i0 + r] = s2 * LOG2E;
        }
    }

    {   // HTt tiled write
        const int n = tid >> 1, ih = tid & 1;
        u16x8 p0, p1;
        #pragma unroll
        for (int v = 0; v < 8; ++v) {
            p0[v] = __builtin_bit_cast(unsigned short, (bf16)hl[ih * 16 + v][n]);
            p1[v] = __builtin_bit_cast(unsigned short, (bf16)hl[ih * 16 + 8 + v][n]);
        }
        bf16* base = HTt + (size_t)blockIdx.x * 4096 + n * 32 + ih * 16;
        *(u16x8*)base       = p0;
        *(u16x8*)(base + 8) = p1;
    }
}

// ---------------------------------------------------------------------------
// FUSED adj-stream + masked-softmax-attention partials, v2 (no ballot).
// Fragment layout fact: for mfma_f32_16x16x32_bf16, lane (m,q) holds
// A[m][q*8+t] — i.e. 8 CONSECUTIVE k (=j) indices of ONE row. So each lane
// can load its own adj dwords directly:
//   lane (m,q) streams row (rbase+m), reading dwordx4 pairs at byte q*32
//   within each 128-B step. The two dwordx4 of a 16-row group tile a full
//   128-B line per row per step -> identical DRAM traffic, 4x fewer load
//   instructions, ZERO cross-lane ops (no ballot/park/bpermute), and the
//   load->use chain is one v_cmp+cndmask instead of 16 loads->16 ballots->
//   2 bpermutes. Distance-1 register prefetch hides HBM latency under the
//   exp2+MFMA block. jc = bid & 7 pins each XCD to one L2-resident HTt slice.
// ---------------------------------------------------------------------------
__global__ __launch_bounds__(256, 4)
void gat_attn(const int* __restrict__ adj, const bf16* __restrict__ HTt,
              const float* __restrict__ e1c, const float* __restrict__ e2c,
              float* __restrict__ numP, float* __restrict__ denP)
{
    const int tid  = threadIdx.x;
    const int wave = tid >> 6;
    const int lane = tid & 63;
    const int m    = lane & 15;
    const int q    = lane >> 4;
    const int jc   = blockIdx.x & (JSPLIT - 1);
    const int ig   = blockIdx.x / JSPLIT;
    const int rbase = ig * 64 + wave * 16;
    const int j0    = jc * CHUNK;

    const float e1 = e1c[rbase + m];
    // lane (m,q): row rbase+m, 8 consecutive j at q*8 within each 32-j step
    const int*   ap = adj + (size_t)(rbase + m) * NN + j0 + q * 8;
    const float* pe = e2c + j0 + q * 8;
    const bf16*  pb = HTt + (size_t)(j0 >> 5) * 4096 + m * 32 + q * 8;

    f32x4 acc[8] = {};
    float rs = 0.f;

    // prologue: step 0 adj in flight
    i32x4 va = *(const i32x4*)(ap);
    i32x4 vb = *(const i32x4*)(ap + 4);

    #pragma unroll 4
    for (int s = 0; s < CHUNK / 32; ++s) {      // 32 steps of 32 j
        const int j = s * 32;
        // prefetch next step (wraps to step 0 on the last iter: in-bounds, L1-hot)
        const int jn = ((s + 1) & (CHUNK / 32 - 1)) * 32;
        const i32x4 van = *(const i32x4*)(ap + jn);
        const i32x4 vbn = *(const i32x4*)(ap + jn + 4);

        const f32x4 e2a = *(const f32x4*)(pe + j);
        const f32x4 e2b = *(const f32x4*)(pe + j + 4);

        bf16x8 af;   // A[m][k=q*8+t], leaky-relu in log2 domain, adj-masked
        #pragma unroll
        for (int t = 0; t < 4; ++t) {
            float sv = e1 + e2a[t];
            sv = fmaxf(sv, ALPHA * sv);
            const float p = (va[t] != 0) ? __builtin_amdgcn_exp2f(sv) : 0.f;
            rs += p;
            af[t] = (bf16)p;
        }
        #pragma unroll
        for (int t = 0; t < 4; ++t) {
            float sv = e1 + e2b[t];
            sv = fmaxf(sv, ALPHA * sv);
            const float p = (vb[t] != 0) ? __builtin_amdgcn_exp2f(sv) : 0.f;
            rs += p;
            af[4 + t] = (bf16)p;
        }

        const bf16* pbs = pb + (size_t)(j >> 5) * 4096;
        #pragma unroll
        for (int t = 0; t < 8; ++t) {
            const bf16x8 b = __builtin_bit_cast(bf16x8, *(const u32x4*)(pbs + t * 512));
            acc[t] = __builtin_amdgcn_mfma_f32_16x16x32_bf16(af, b, acc[t], 0, 0, 0);
        }

        va = van; vb = vbn;
    }

    // row-sum: lanes {m, m+16, m+32, m+48} hold the 4 q-slices of row m
    rs += __shfl_xor(rs, 16);
    rs += __shfl_xor(rs, 32);
    if (lane < 16) denP[(size_t)jc * NN + rbase + m] = rs;

    // C/D layout: col = lane&15, row = q*4 + r -> unique partial slot
    #pragma unroll
    for (int t = 0; t < 8; ++t)
        #pragma unroll
        for (int r = 0; r < 4; ++r)
            numP[((size_t)jc * NN + rbase + q * 4 + r) * OUTF + t * 16 + m] = acc[t][r];
}

// ---------------------------------------------------------------------------
// Finalize: out = elu( (sum_s numP) / (sum_s denP) )
// ---------------------------------------------------------------------------
__global__ __launch_bounds__(256)
void gat_fin(const float* __restrict__ numP, const float* __restrict__ denP,
             const int* __restrict__ flag, void* __restrict__ outv)
{
    const int g  = blockIdx.x * 256 + threadIdx.x;   // one thread per 4 elems
    const int i  = g >> 5;
    const int c4 = g & 31;
    float d = 0.f;
    f32x4 v = {0.f, 0.f, 0.f, 0.f};
    #pragma unroll
    for (int s = 0; s < JSPLIT; ++s) {
        d += denP[(size_t)s * NN + i];
        const f32x4 u = *(const f32x4*)(numP + ((size_t)s * NN + i) * OUTF + c4 * 4);
        #pragma unroll
        for (int t = 0; t < 4; ++t) v[t] += u[t];
    }
    #pragma unroll
    for (int t = 0; t < 4; ++t) {
        const float u = v[t] / d;
        v[t] = (u > 0.f) ? u : __builtin_amdgcn_exp2f(u * LOG2E) - 1.f;  // elu
    }
    const size_t off = (size_t)i * OUTF + c4 * 4;
    if (*flag) {
        *(f32x4*)((float*)outv + off) = v;
    } else {
        u16x4 pk;
        #pragma unroll
        for (int t = 0; t < 4; ++t)
            pk[t] = __builtin_bit_cast(unsigned short, (bf16)v[t]);
        *(u16x4*)((__hip_bfloat16*)outv + off) = pk;
    }
}

// ---------------------------------------------------------------------------
extern "C" void kernel_launch(void* const* d_in, const int* in_sizes, int n_in,
                              void* d_out, int out_size, void* d_ws, size_t ws_size,
                              hipStream_t stream)
{
    const int* adj = (const int*)d_in[1];

    // ws layout (bytes):
    // HTt 2MB | e1c 32KB | e2c 32KB | flag 256B | TT 64KB | numP 32MB | denP 256KB
    char* w = (char*)d_ws;
    bf16*  HTt   = (bf16*)w;   w += (size_t)OUTF * NN * 2;
    float* e1c   = (float*)w;  w += NN * 4;
    float* e2c   = (float*)w;  w += NN * 4;
    int*   flag  = (int*)w;    w += 256;
    bf16*  TT    = (bf16*)w;   w += (size_t)OUTF * INF_ * 2;
    float* numP  = (float*)w;  w += (size_t)JSPLIT * NN * OUTF * 4;
    float* denP  = (float*)w;

    gat_detect<<<1, 64, 0, stream>>>((const unsigned short*)d_in[0], flag);

    gat_tt<float, 1><<<OUTF, INF_, 0, stream>>>((const float*)d_in[2], flag, TT);
    gat_tt<bf16, 0><<<OUTF, INF_, 0, stream>>>((const bf16*)d_in[2], flag, TT);

    gat_proj_t<float, 1><<<NN / 32, 256, 0, stream>>>(
        (const float*)d_in[0], TT, (const float*)d_in[3], flag, HTt, e1c, e2c);
    gat_proj_t<bf16, 0><<<NN / 32, 256, 0, stream>>>(
        (const bf16*)d_in[0], TT, (const bf16*)d_in[3], flag, HTt, e1c, e2c);

    gat_attn<<<(NN / 64) * JSPLIT, 256, 0, stream>>>(adj, HTt, e1c, e2c, numP, denP);

    gat_fin<<<NN * OUTF / 4 / 256, 256, 0, stream>>>(numP, denP, flag, d_out);
}

// Round 2
// 418.990 us; speedup vs baseline: 1.0638x; 1.0638x over previous
//
#include <hip/hip_runtime.h>
#include <hip/hip_bf16.h>
#include <cstdint>
#include <cstddef>

#define NN     8192
#define INF_   256
#define OUTF   128
#define ALPHA  0.2f
#define LOG2E  1.4426950408889634f
#define JSPLIT 16
#define CHUNK  (NN / JSPLIT)     // 512 j per block
#define NS     (CHUNK / 32)      // 16 steps of 32 j

typedef __bf16 bf16;
typedef unsigned int u32;
typedef unsigned long long u64;
typedef __attribute__((ext_vector_type(8))) __bf16 bf16x8;
typedef __attribute__((ext_vector_type(4))) float f32x4;
typedef __attribute__((ext_vector_type(4))) int i32x4;
typedef __attribute__((ext_vector_type(4))) unsigned int u32x4;
typedef __attribute__((ext_vector_type(8))) unsigned short u16x8;
typedef __attribute__((ext_vector_type(4))) unsigned short u16x4;

// ---------------------------------------------------------------------------
// Dtype detector: read x's first 2048 uint16s as bf16. fp32 storage -> words
// are fp32 mantissa fragments -> huge exponents; bf16 storage -> N(0,1).
// flag = 1 -> tensors are fp32 (confirmed R2-R7); 0 -> bf16.
// ---------------------------------------------------------------------------
__global__ void gat_detect(const unsigned short* __restrict__ xr, int* __restrict__ flag)
{
    const int lane = threadIdx.x & 63;
    float m = 0.f;
    #pragma unroll
    for (int t = 0; t < 32; ++t) {
        const unsigned short u = xr[lane * 32 + t];
        const float v = fabsf((float)__builtin_bit_cast(bf16, u));
        if (v == v) m = fmaxf(m, v);
    }
    #pragma unroll
    for (int d = 1; d < 64; d <<= 1) m = fmaxf(m, __shfl_xor(m, d));
    if (lane == 0) *flag = (m > 100.f) ? 1 : 0;
}

// dtype-generic helpers ------------------------------------------------------
static __device__ __forceinline__ bf16  loadS(const bf16* p)  { return *p; }
static __device__ __forceinline__ bf16  loadS(const float* p) { return (bf16)*p; }
static __device__ __forceinline__ float loadF(const bf16* p)  { return (float)*p; }
static __device__ __forceinline__ float loadF(const float* p) { return *p; }
static __device__ __forceinline__ void load4(const float* p, bf16* d) {
    const f32x4 v = *(const f32x4*)p;
    #pragma unroll
    for (int t = 0; t < 4; ++t) d[t] = (bf16)v[t];
}
static __device__ __forceinline__ void load4(const bf16* p, bf16* d) {
    *(u16x4*)d = *(const u16x4*)p;
}

// async global->LDS, 16 B per lane (dest = wave-uniform base + lane*16)
typedef __attribute__((address_space(1))) const unsigned int gas_u32;
typedef __attribute__((address_space(3))) unsigned int las_u32;
static __device__ __forceinline__ void gll16(const void* g, void* l)
{
    __builtin_amdgcn_global_load_lds((gas_u32*)g, (las_u32*)l, 16, 0, 0);
}

// ---------------------------------------------------------------------------
// trans transpose: TT[n][k] = bf16(trans[k][n]).
// ---------------------------------------------------------------------------
template <typename T, int WANT>
__global__ void gat_tt(const T* __restrict__ trans, const int* __restrict__ flag,
                       bf16* __restrict__ TT)
{
    if (*flag != WANT) return;
    const int n = blockIdx.x;      // 0..127
    const int k = threadIdx.x;     // 0..255
    TT[n * INF_ + k] = loadS(trans + k * OUTF + n);
}

// ---------------------------------------------------------------------------
// Projection: h = x @ trans via LDS-staged MFMA. Outputs:
//   HTt tiled: HTt[i>>5][n][i&31]  (attn b-frag loads become contiguous 1KB)
//   e1c/e2c (pre-scaled by log2e)
// ---------------------------------------------------------------------------
template <typename T, int WANT>
__global__ __launch_bounds__(256, 1)
void gat_proj_t(const T* __restrict__ x, const bf16* __restrict__ TT,
                const T* __restrict__ aw, const int* __restrict__ flag,
                bf16* __restrict__ HTt, float* __restrict__ e1c, float* __restrict__ e2c)
{
    if (*flag != WANT) return;

    __shared__ bf16  xs[32][264];
    __shared__ bf16  TTs[128][264];
    __shared__ float hl[32][129];

    const int tid  = threadIdx.x;
    const int wave = tid >> 6;
    const int lane = tid & 63;
    const int m    = lane & 15;
    const int q    = lane >> 4;
    const int i0   = blockIdx.x * 32;

    #pragma unroll
    for (int it = 0; it < 8; ++it) {
        const int e = it * 1024 + tid * 4;
        bf16 tmp[4];
        load4(x + (size_t)i0 * INF_ + e, tmp);
        *(u16x4*)&xs[e >> 8][e & 255] = *(u16x4*)tmp;
    }
    #pragma unroll
    for (int it = 0; it < 16; ++it) {
        const int e = it * 2048 + tid * 8;
        *(u16x8*)&TTs[e >> 8][e & 255] = *(const u16x8*)(TT + e);
    }
    __syncthreads();

    const int rh = wave & 1, fh = wave >> 1;
    f32x4 acc[4] = {};
    #pragma unroll
    for (int ks = 0; ks < INF_; ks += 32) {
        const bf16x8 a = *(const bf16x8*)&xs[rh * 16 + m][ks + q * 8];
        #pragma unroll
        for (int tn = 0; tn < 4; ++tn) {
            const bf16x8 b = *(const bf16x8*)&TTs[fh * 64 + tn * 16 + m][ks + q * 8];
            acc[tn] = __builtin_amdgcn_mfma_f32_16x16x32_bf16(a, b, acc[tn], 0, 0, 0);
        }
    }

    #pragma unroll
    for (int tn = 0; tn < 4; ++tn)
        #pragma unroll
        for (int r = 0; r < 4; ++r)
            hl[rh * 16 + q * 4 + r][fh * 64 + tn * 16 + m] = acc[tn][r];
    __syncthreads();

    {   // e1/e2
        const int r = tid >> 3, seg = tid & 7;
        float s1 = 0.f, s2 = 0.f;
        #pragma unroll
        for (int u = 0; u < 16; ++u) {
            const float hv = hl[r][seg * 16 + u];
            s1 += hv * loadF(aw + seg * 16 + u);
            s2 += hv * loadF(aw + OUTF + seg * 16 + u);
        }
        #pragma unroll
        for (int d = 1; d < 8; d <<= 1) {
            s1 += __shfl_xor(s1, d);
            s2 += __shfl_xor(s2, d);
        }
        if (seg == 0) {
            e1c[i0 + r] = s1 * LOG2E;
            e2c[i0 + r] = s2 * LOG2E;
        }
    }

    {   // HTt tiled write
        const int n = tid >> 1, ih = tid & 1;
        u16x8 p0, p1;
        #pragma unroll
        for (int v = 0; v < 8; ++v) {
            p0[v] = __builtin_bit_cast(unsigned short, (bf16)hl[ih * 16 + v][n]);
            p1[v] = __builtin_bit_cast(unsigned short, (bf16)hl[ih * 16 + 8 + v][n]);
        }
        bf16* base = HTt + (size_t)blockIdx.x * 4096 + n * 32 + ih * 16;
        *(u16x8*)base       = p0;
        *(u16x8*)(base + 8) = p1;
    }
}

// ---------------------------------------------------------------------------
// FUSED adj-stream + masked-softmax-attention partials, v3.
// R1 diagnosis: the b-fragment (HTt) re-read stream was 1 GB (4 waves x 8 KB
// per block-step, nothing shared) vs adj's 256 MB; L2 is continuously evicted
// by the adj stream, so all of it hits the LLC -> memory system saturated at
// ~7 TB/s on eliminable traffic (MfmaUtil 4%, VALUBusy 11%, hbm 1.24 TB/s).
// Fix: (a) stage each 8 KB HT step-tile in LDS via global_load_lds, double-
// buffered, shared by all 4 waves; (b) RG=2: each wave computes 2 row-groups
// (32 rows) against the same b-frags -> HTt traffic 1 GB -> 128 MB (/8);
// (c) e2 slice staged once in LDS (broadcast reads, conflict-free);
// (d) adj stays per-lane register loads, distance-1; the __syncthreads at
// step end (vmcnt(0)+barrier) doubles as the staging wait, and 4 blocks/CU
// of independent phase cover the residual latency. adj (256 MB, read once,
// coalesced) becomes the pacing stream: floor ~41 us at 6.3 TB/s.
// LDS layout hts[buf][qq*1024 + n*8 + t] == HT[j=qq*8+t][n]: b-frag ds_reads
// are 4 contiguous 256 B runs (b128 BW floor, no swizzle needed); the gll
// dest (d2*16, d2 = qq*128+n) is exactly linear in (qq,n) so the wave-uniform
// dest constraint is satisfied with per-lane source addresses.
// ---------------------------------------------------------------------------
__global__ __launch_bounds__(256, 4)
void gat_attn(const int* __restrict__ adj, const bf16* __restrict__ HTt,
              const float* __restrict__ e1c, const float* __restrict__ e2c,
              float* __restrict__ numP, float* __restrict__ denP)
{
    __shared__ bf16  hts[2][4096];   // 2 x 8 KB HT step tiles
    __shared__ float e2s[CHUNK];     // 2 KB e2 slice (pre-scaled by log2e)

    const int tid  = threadIdx.x;
    const int wave = tid >> 6;
    const int lane = tid & 63;
    const int m    = lane & 15;
    const int q    = lane >> 4;
    const int jc   = blockIdx.x & (JSPLIT - 1);
    const int ig   = blockIdx.x / JSPLIT;
    const int rbase = ig * 128 + wave * 32;   // 2 row-groups: +0..15, +16..31
    const int j0    = jc * CHUNK;

    // HT staging geometry: thread covers dest slots d2 = k*256 + tid (k=0,1);
    // dest byte d2*16 = qq*2048 + n*16 with qq = d2>>7, n = d2&127;
    // src element = n*32 + qq*8 inside the [n][32] global tile.
    const int hn = tid & 127;
    const int hq = tid >> 7;
    const bf16* tbase = HTt + (size_t)(jc * NS) * 4096;

    auto stageHT = [&](int s, int b) {
        const bf16* ts = tbase + (size_t)s * 4096;
        gll16(ts + hn * 32 + hq * 8,       &hts[b][(wave * 64) * 8]);
        gll16(ts + hn * 32 + (hq + 2) * 8, &hts[b][(256 + wave * 64) * 8]);
    };

    const float e1a = e1c[rbase + m];
    const float e1b = e1c[rbase + 16 + m];
    const int* ap0 = adj + (size_t)(rbase + m) * NN + j0 + q * 8;
    const int* ap1 = adj + (size_t)(rbase + 16 + m) * NN + j0 + q * 8;

    f32x4 acc0[8] = {};
    f32x4 acc1[8] = {};
    float rs0 = 0.f, rs1 = 0.f;
    i32x4 adjv[2][4];   // [parity][g0lo,g0hi,g1lo,g1hi]; full unroll -> regs

    // ---- prologue: tile 0 + adj set 0 in flight, e2 slice to LDS
    stageHT(0, 0);
    adjv[0][0] = *(const i32x4*)(ap0);
    adjv[0][1] = *(const i32x4*)(ap0 + 4);
    adjv[0][2] = *(const i32x4*)(ap1);
    adjv[0][3] = *(const i32x4*)(ap1 + 4);
    {
        const float2 ev = *(const float2*)(e2c + j0 + tid * 2);
        *(float2*)&e2s[tid * 2] = ev;
    }
    __syncthreads();   // drains vmcnt(0): tile 0 + adj set 0 ready

    #pragma unroll
    for (int s = 0; s < NS; ++s) {
        const int cur = s & 1;

        if (s + 1 < NS) {
            // issue next HT tile + next adj set first: their completion is
            // covered by this step's compute + the end-of-step drain
            stageHT(s + 1, cur ^ 1);
            const int o = (s + 1) * 32;
            adjv[cur ^ 1][0] = *(const i32x4*)(ap0 + o);
            adjv[cur ^ 1][1] = *(const i32x4*)(ap0 + o + 4);
            adjv[cur ^ 1][2] = *(const i32x4*)(ap1 + o);
            adjv[cur ^ 1][3] = *(const i32x4*)(ap1 + o + 4);
        }

        const f32x4 e2a = *(const f32x4*)&e2s[s * 32 + q * 8];
        const f32x4 e2b = *(const f32x4*)&e2s[s * 32 + q * 8 + 4];

        bf16x8 af0, af1;   // A[m][k=q*8+t], leaky-relu in log2 domain, masked
        #pragma unroll
        for (int t = 0; t < 4; ++t) {
            float sv0 = e1a + e2a[t];
            sv0 = fmaxf(sv0, ALPHA * sv0);
            const float p0 = (adjv[cur][0][t] != 0) ? __builtin_amdgcn_exp2f(sv0) : 0.f;
            rs0 += p0; af0[t] = (bf16)p0;

            float sv1 = e1b + e2a[t];
            sv1 = fmaxf(sv1, ALPHA * sv1);
            const float p1 = (adjv[cur][2][t] != 0) ? __builtin_amdgcn_exp2f(sv1) : 0.f;
            rs1 += p1; af1[t] = (bf16)p1;
        }
        #pragma unroll
        for (int t = 0; t < 4; ++t) {
            float sv0 = e1a + e2b[t];
            sv0 = fmaxf(sv0, ALPHA * sv0);
            const float p0 = (adjv[cur][1][t] != 0) ? __builtin_amdgcn_exp2f(sv0) : 0.f;
            rs0 += p0; af0[4 + t] = (bf16)p0;

            float sv1 = e1b + e2b[t];
            sv1 = fmaxf(sv1, ALPHA * sv1);
            const float p1 = (adjv[cur][3][t] != 0) ? __builtin_amdgcn_exp2f(sv1) : 0.f;
            rs1 += p1; af1[4 + t] = (bf16)p1;
        }

        // 16 MFMAs: 8 shared b-frags from LDS serve both row-groups
        #pragma unroll
        for (int t = 0; t < 8; ++t) {
            const bf16x8 b = *(const bf16x8*)&hts[cur][q * 1024 + (t * 16 + m) * 8];
            acc0[t] = __builtin_amdgcn_mfma_f32_16x16x32_bf16(af0, b, acc0[t], 0, 0, 0);
            acc1[t] = __builtin_amdgcn_mfma_f32_16x16x32_bf16(af1, b, acc1[t], 0, 0, 0);
        }

        if (s + 1 < NS) __syncthreads();   // vmcnt(0)+barrier: next tile ready
    }

    // row-sums: lanes {m, m+16, m+32, m+48} hold the 4 q-slices of row m
    rs0 += __shfl_xor(rs0, 16);
    rs0 += __shfl_xor(rs0, 32);
    rs1 += __shfl_xor(rs1, 16);
    rs1 += __shfl_xor(rs1, 32);
    if (lane < 16) {
        denP[(size_t)jc * NN + rbase + m]      = rs0;
        denP[(size_t)jc * NN + rbase + 16 + m] = rs1;
    }

    // C/D layout: col = lane&15, row = q*4 + r -> unique partial slot
    #pragma unroll
    for (int t = 0; t < 8; ++t)
        #pragma unroll
        for (int r = 0; r < 4; ++r) {
            numP[((size_t)jc * NN + rbase + q * 4 + r) * OUTF + t * 16 + m]      = acc0[t][r];
            numP[((size_t)jc * NN + rbase + 16 + q * 4 + r) * OUTF + t * 16 + m] = acc1[t][r];
        }
}

// ---------------------------------------------------------------------------
// Finalize: out = elu( (sum_s numP) / (sum_s denP) )
// ---------------------------------------------------------------------------
__global__ __launch_bounds__(256)
void gat_fin(const float* __restrict__ numP, const float* __restrict__ denP,
             const int* __restrict__ flag, void* __restrict__ outv)
{
    const int g  = blockIdx.x * 256 + threadIdx.x;   // one thread per 4 elems
    const int i  = g >> 5;
    const int c4 = g & 31;
    float d = 0.f;
    f32x4 v = {0.f, 0.f, 0.f, 0.f};
    #pragma unroll
    for (int s = 0; s < JSPLIT; ++s) {
        d += denP[(size_t)s * NN + i];
        const f32x4 u = *(const f32x4*)(numP + ((size_t)s * NN + i) * OUTF + c4 * 4);
        #pragma unroll
        for (int t = 0; t < 4; ++t) v[t] += u[t];
    }
    #pragma unroll
    for (int t = 0; t < 4; ++t) {
        const float u = v[t] / d;
        v[t] = (u > 0.f) ? u : __builtin_amdgcn_exp2f(u * LOG2E) - 1.f;  // elu
    }
    const size_t off = (size_t)i * OUTF + c4 * 4;
    if (*flag) {
        *(f32x4*)((float*)outv + off) = v;
    } else {
        u16x4 pk;
        #pragma unroll
        for (int t = 0; t < 4; ++t)
            pk[t] = __builtin_bit_cast(unsigned short, (bf16)v[t]);
        *(u16x4*)((__hip_bfloat16*)outv + off) = pk;
    }
}

// ---------------------------------------------------------------------------
extern "C" void kernel_launch(void* const* d_in, const int* in_sizes, int n_in,
                              void* d_out, int out_size, void* d_ws, size_t ws_size,
                              hipStream_t stream)
{
    const int* adj = (const int*)d_in[1];

    // ws layout (bytes):
    // HTt 2MB | e1c 32KB | e2c 32KB | flag 256B | TT 64KB | numP 64MB | denP 512KB
    char* w = (char*)d_ws;
    bf16*  HTt   = (bf16*)w;   w += (size_t)OUTF * NN * 2;
    float* e1c   = (float*)w;  w += NN * 4;
    float* e2c   = (float*)w;  w += NN * 4;
    int*   flag  = (int*)w;    w += 256;
    bf16*  TT    = (bf16*)w;   w += (size_t)OUTF * INF_ * 2;
    float* numP  = (float*)w;  w += (size_t)JSPLIT * NN * OUTF * 4;
    float* denP  = (float*)w;

    gat_detect<<<1, 64, 0, stream>>>((const unsigned short*)d_in[0], flag);

    gat_tt<float, 1><<<OUTF, INF_, 0, stream>>>((const float*)d_in[2], flag, TT);
    gat_tt<bf16, 0><<<OUTF, INF_, 0, stream>>>((const bf16*)d_in[2], flag, TT);

    gat_proj_t<float, 1><<<NN / 32, 256, 0, stream>>>(
        (const float*)d_in[0], TT, (const float*)d_in[3], flag, HTt, e1c, e2c);
    gat_proj_t<bf16, 0><<<NN / 32, 256, 0, stream>>>(
        (const bf16*)d_in[0], TT, (const bf16*)d_in[3], flag, HTt, e1c, e2c);

    gat_attn<<<(NN / 128) * JSPLIT, 256, 0, stream>>>(adj, HTt, e1c, e2c, numP, denP);

    gat_fin<<<NN * OUTF / 4 / 256, 256, 0, stream>>>(numP, denP, flag, d_out);
}